// Round 3
// baseline (232.098 us; speedup 1.0000x reference)
//
#include <hip/hip_runtime.h>
#include <stdint.h>

// Problem constants (B, N, H, L) = (4096, 512, 1024, 8)
static constexpr int B_DIM = 4096;
static constexpr int N_DIM = 512;
static constexpr int H_DIM = 1024;
static constexpr int L_DIM = 8;
static constexpr int HL    = H_DIM * L_DIM;   // 8192
static constexpr int KC    = 2 * N_DIM;       // 1024 combined K for [x | x^2]

typedef __attribute__((ext_vector_type(8))) short short8;  // 8 bf16 = 4 VGPRs
typedef __attribute__((ext_vector_type(4))) float f32x4;

#define BK 64   // 8 chunks of 8 bf16 per row

// round-to-nearest-even fp32 -> bf16 (bit pattern)
__device__ __forceinline__ uint16_t f2bf(float f) {
  uint32_t u = __float_as_uint(f);
  u += 0x7fffu + ((u >> 16) & 1u);
  return (uint16_t)(u >> 16);
}

__device__ __forceinline__ void stage16(const uint16_t* g, uint16_t* l) {
  __builtin_amdgcn_global_load_lds(
      (const __attribute__((address_space(1))) void*)g,
      (__attribute__((address_space(3))) void*)l, 16, 0, 0);
}

// ---------- fused prep kernel ----------
// region 0: betab = bf16(beta)                              (HL*N)
// region 1: xcomb[b,0:512]=bf16(x), [512:1024]=bf16(x^2)    (B*N)
// region 2: combW[h,0:512]=bf16(W), [512:1024]=bf16(-0.5*sum_l beta^2) (H*N)
// region 3: out = 0  (float4 stores, B*H/4)   -- needed: both GEMM epilogues atomicAdd
__global__ void prep_kernel(const float* __restrict__ x, const float* __restrict__ beta,
                            const float* __restrict__ W,
                            uint16_t* __restrict__ xcomb, uint16_t* __restrict__ betab,
                            uint16_t* __restrict__ combW, float* __restrict__ out) {
  int idx = blockIdx.x * 256 + threadIdx.x;
  if (idx < HL * N_DIM) {                    // beta cast
    betab[idx] = f2bf(beta[idx]);
    return;
  }
  idx -= HL * N_DIM;
  if (idx < B_DIM * N_DIM) {                 // x | x^2
    int b = idx >> 9, n = idx & 511;
    float v = x[idx];
    xcomb[(size_t)b * KC + n]         = f2bf(v);
    xcomb[(size_t)b * KC + N_DIM + n] = f2bf(v * v);
    return;
  }
  idx -= B_DIM * N_DIM;
  if (idx < H_DIM * N_DIM) {                 // W | -0.5*sum_l beta^2
    int h = idx >> 9, n = idx & 511;
    combW[(size_t)h * KC + n] = f2bf(W[idx]);
    float s = 0.f;
#pragma unroll
    for (int l = 0; l < L_DIM; ++l) {
      float v = beta[((size_t)h * L_DIM + l) * N_DIM + n];
      s += v * v;
    }
    combW[(size_t)h * KC + N_DIM + n] = f2bf(-0.5f * s);
    return;
  }
  idx -= H_DIM * N_DIM;                      // zero out
  f32x4 z = {0.f, 0.f, 0.f, 0.f};
  ((f32x4*)out)[idx] = z;
}

// ---------- merged GEMM ----------
// bx <  64 : FM     — C[b,hl] over K=512 (xcomb low half x betab), 128x128 tile,
//                     epilogue: atomicAdd(out[b,h], 0.5*sum_l C^2)
// bx >= 64 : linear — C[b,h] over K=1024 ([x|x^2] x combW), 128x64 tile,
//                     epilogue: atomicAdd(out[b,h], C + bias[h])
// LDS swizzle: row m (BK=64 = 8 chunks of 16B): source chunk c stored at
// slot c ^ (m&7). Staging permutes the SOURCE address (global_load_lds dest
// must stay lane-contiguous); readers apply the same xor. Quad's 16 lanes
// spread across all 32 banks, 2-way (free per m136).
__global__ __launch_bounds__(256) void fused_gemm_kernel(
    const uint16_t* __restrict__ xcomb,   // (B, KC)
    const uint16_t* __restrict__ betab,   // (HL, N)
    const uint16_t* __restrict__ combW,   // (H, KC)
    const float* __restrict__ bias,       // (H,)
    float* __restrict__ out)              // (B, H), pre-zeroed
{
  __shared__ __align__(16) uint16_t As[128 * BK];  // 16 KB
  __shared__ __align__(16) uint16_t Bs[128 * BK];  // 16 KB (linear uses half)

  const int tid  = threadIdx.x;
  const int lane = tid & 63;
  const int wave = tid >> 6;
  const int wm = wave >> 1, wn = wave & 1;
  const int fr   = lane & 15;
  const int quad = lane >> 4;
  const int row0 = blockIdx.y * 128;

  if (blockIdx.x < 64) {
    // ------- FM part: 128x128, K=512 -------
    const int col0 = blockIdx.x * 128;
    f32x4 acc[4][4] = {};
    for (int kt = 0; kt < N_DIM; kt += BK) {
#pragma unroll
      for (int u = 0; u < 4; ++u) {   // A: 1024 chunks
        int s = tid + u * 256, m = s >> 3, cp = s & 7, c = cp ^ (m & 7);
        stage16(xcomb + (size_t)(row0 + m) * KC + kt + c * 8, As + s * 8);
      }
#pragma unroll
      for (int u = 0; u < 4; ++u) {   // B: 1024 chunks
        int s = tid + u * 256, m = s >> 3, cp = s & 7, c = cp ^ (m & 7);
        stage16(betab + (size_t)(col0 + m) * N_DIM + kt + c * 8, Bs + s * 8);
      }
      __syncthreads();
#pragma unroll
      for (int kk = 0; kk < BK; kk += 32) {
        short8 af[4], bf[4];
#pragma unroll
        for (int i = 0; i < 4; ++i) {
          int m = wm * 64 + i * 16 + fr;
          int cp = ((kk >> 3) + quad) ^ (m & 7);
          af[i] = *(const short8*)(As + (m * 8 + cp) * 8);
        }
#pragma unroll
        for (int j = 0; j < 4; ++j) {
          int m = wn * 64 + j * 16 + fr;
          int cp = ((kk >> 3) + quad) ^ (m & 7);
          bf[j] = *(const short8*)(Bs + (m * 8 + cp) * 8);
        }
#pragma unroll
        for (int i = 0; i < 4; ++i)
#pragma unroll
          for (int j = 0; j < 4; ++j)
            acc[i][j] = __builtin_amdgcn_mfma_f32_16x16x32_bf16(af[i], bf[j], acc[i][j], 0, 0, 0);
      }
      __syncthreads();
    }
    // epilogue: C/D layout col=lane&15, row=quad*4+reg. col here is hl = h*8+l.
    const int hcol0 = blockIdx.x * 16;
#pragma unroll
    for (int i = 0; i < 4; ++i) {
#pragma unroll
      for (int j = 0; j < 4; ++j) {
        const int h_in = wn * 8 + j * 2 + (fr >> 3);
        const int rowb = row0 + wm * 64 + i * 16 + quad * 4;
#pragma unroll
        for (int r = 0; r < 4; ++r) {
          float v = acc[i][j][r];
          v = v * v;
          v += __shfl_xor(v, 1);   // butterfly over l = lane bits 0..2
          v += __shfl_xor(v, 2);
          v += __shfl_xor(v, 4);
          if ((lane & 7) == 0)
            atomicAdd(out + (size_t)(rowb + r) * H_DIM + hcol0 + h_in, 0.5f * v);
        }
      }
    }
  } else {
    // ------- linear part: 128x64, K=1024 -------
    const int col0 = (blockIdx.x - 64) * 64;
    f32x4 acc[4][2] = {};
    for (int kt = 0; kt < KC; kt += BK) {
#pragma unroll
      for (int u = 0; u < 4; ++u) {   // A: 1024 chunks
        int s = tid + u * 256, m = s >> 3, cp = s & 7, c = cp ^ (m & 7);
        stage16(xcomb + (size_t)(row0 + m) * KC + kt + c * 8, As + s * 8);
      }
#pragma unroll
      for (int u = 0; u < 2; ++u) {   // B: 512 chunks (64 rows)
        int s = tid + u * 256, m = s >> 3, cp = s & 7, c = cp ^ (m & 7);
        stage16(combW + (size_t)(col0 + m) * KC + kt + c * 8, Bs + s * 8);
      }
      __syncthreads();
#pragma unroll
      for (int kk = 0; kk < BK; kk += 32) {
        short8 af[4], bf[2];
#pragma unroll
        for (int i = 0; i < 4; ++i) {
          int m = wm * 64 + i * 16 + fr;
          int cp = ((kk >> 3) + quad) ^ (m & 7);
          af[i] = *(const short8*)(As + (m * 8 + cp) * 8);
        }
#pragma unroll
        for (int j = 0; j < 2; ++j) {
          int m = wn * 32 + j * 16 + fr;
          int cp = ((kk >> 3) + quad) ^ (m & 7);
          bf[j] = *(const short8*)(Bs + (m * 8 + cp) * 8);
        }
#pragma unroll
        for (int i = 0; i < 4; ++i)
#pragma unroll
          for (int j = 0; j < 2; ++j)
            acc[i][j] = __builtin_amdgcn_mfma_f32_16x16x32_bf16(af[i], bf[j], acc[i][j], 0, 0, 0);
      }
      __syncthreads();
    }
#pragma unroll
    for (int i = 0; i < 4; ++i) {
#pragma unroll
      for (int j = 0; j < 2; ++j) {
        const int col  = col0 + wn * 32 + j * 16 + fr;
        const int rowb = row0 + wm * 64 + i * 16 + quad * 4;
        const float bs = bias[col];
#pragma unroll
        for (int r = 0; r < 4; ++r)
          atomicAdd(out + (size_t)(rowb + r) * H_DIM + col, acc[i][j][r] + bs);
      }
    }
  }
}

extern "C" void kernel_launch(void* const* d_in, const int* in_sizes, int n_in,
                              void* d_out, int out_size, void* d_ws, size_t ws_size,
                              hipStream_t stream) {
  const float* x    = (const float*)d_in[0];  // (4096, 512)
  const float* beta = (const float*)d_in[1];  // (1024, 8, 512)
  const float* W    = (const float*)d_in[2];  // (1024, 512)
  const float* bias = (const float*)d_in[3];  // (1024,)
  float* out = (float*)d_out;                 // (4096, 1024)

  uint16_t* xcomb = (uint16_t*)d_ws;                        // 4096*1024 bf16 = 8 MB
  uint16_t* betab = xcomb + (size_t)B_DIM * KC;             // 8192*512  bf16 = 8 MB
  uint16_t* combW = betab + (size_t)HL * N_DIM;             // 1024*1024 bf16 = 2 MB

  // prep: beta cast + x|x^2 + combW + zero(out)
  const int prep_elems = HL * N_DIM + B_DIM * N_DIM + H_DIM * N_DIM + B_DIM * H_DIM / 4;
  prep_kernel<<<(prep_elems + 255) / 256, 256, 0, stream>>>(x, beta, W, xcomb, betab, combW, out);

  // merged GEMM: bx [0,64) = FM 128x128 tiles; bx [64,80) = linear 128x64 tiles
  fused_gemm_kernel<<<dim3(80, 32), 256, 0, stream>>>(xcomb, betab, combW, bias, out);
}

// Round 4
// 178.587 us; speedup vs baseline: 1.2996x; 1.2996x over previous
//
#include <hip/hip_runtime.h>
#include <stdint.h>

// Problem constants (B, N, H, L) = (4096, 512, 1024, 8)
static constexpr int B_DIM = 4096;
static constexpr int N_DIM = 512;
static constexpr int H_DIM = 1024;
static constexpr int L_DIM = 8;
static constexpr int HL    = H_DIM * L_DIM;   // 8192
static constexpr int KC    = 2 * N_DIM;       // 1024 combined K for [x | x^2]

typedef __attribute__((ext_vector_type(8))) short short8;     // 8 bf16 (4 VGPRs)
typedef __attribute__((ext_vector_type(8))) unsigned short u16x8;
typedef __attribute__((ext_vector_type(4))) float f32x4;

#define BK 64   // 8 chunks of 8 bf16 per row

// round-to-nearest-even fp32 -> bf16 (bit pattern)
__device__ __forceinline__ uint16_t f2bf(float f) {
  uint32_t u = __float_as_uint(f);
  u += 0x7fffu + ((u >> 16) & 1u);
  return (uint16_t)(u >> 16);
}

__device__ __forceinline__ void stage16(const uint16_t* g, uint16_t* l) {
  __builtin_amdgcn_global_load_lds(
      (const __attribute__((address_space(1))) void*)g,
      (__attribute__((address_space(3))) void*)l, 16, 0, 0);
}

// ---------- fused prep kernel (8 elems/thread, 16B stores) ----------
// region 0: betab = bf16(beta)                              (HL*N/8 threads)
// region 1: xcomb[b,0:512]=bf16(x), [512:1024]=bf16(x^2)    (B*N/8)
// region 2: combW[h,0:512]=bf16(W), [512:1024]=bf16(-0.5*sum_l beta^2) (H*N/8)
static constexpr int PREP_T0 = HL * N_DIM / 8;       // 524288
static constexpr int PREP_T1 = B_DIM * N_DIM / 8;    // 262144
static constexpr int PREP_T2 = H_DIM * N_DIM / 8;    // 65536

__global__ void prep_kernel(const float* __restrict__ x, const float* __restrict__ beta,
                            const float* __restrict__ W,
                            uint16_t* __restrict__ xcomb, uint16_t* __restrict__ betab,
                            uint16_t* __restrict__ combW) {
  int t = blockIdx.x * 256 + threadIdx.x;
  if (t < PREP_T0) {                           // beta cast
    const f32x4* src = (const f32x4*)(beta + (size_t)t * 8);
    f32x4 a = src[0], b = src[1];
    u16x8 o;
#pragma unroll
    for (int i = 0; i < 4; ++i) { o[i] = f2bf(a[i]); o[4 + i] = f2bf(b[i]); }
    *(u16x8*)(betab + (size_t)t * 8) = o;
    return;
  }
  t -= PREP_T0;
  if (t < PREP_T1) {                           // x | x^2
    int bb = t >> 6, n8 = (t & 63) * 8;
    const f32x4* src = (const f32x4*)(x + (size_t)bb * N_DIM + n8);
    f32x4 a = src[0], b = src[1];
    u16x8 lo, hi;
#pragma unroll
    for (int i = 0; i < 4; ++i) {
      lo[i] = f2bf(a[i]);     lo[4 + i] = f2bf(b[i]);
      hi[i] = f2bf(a[i] * a[i]); hi[4 + i] = f2bf(b[i] * b[i]);
    }
    *(u16x8*)(xcomb + (size_t)bb * KC + n8)         = lo;
    *(u16x8*)(xcomb + (size_t)bb * KC + N_DIM + n8) = hi;
    return;
  }
  t -= PREP_T1;                                // W | -0.5*sum_l beta^2
  int h = t >> 6, n8 = (t & 63) * 8;
  const f32x4* wsrc = (const f32x4*)(W + (size_t)h * N_DIM + n8);
  f32x4 wa = wsrc[0], wb = wsrc[1];
  u16x8 lo;
#pragma unroll
  for (int i = 0; i < 4; ++i) { lo[i] = f2bf(wa[i]); lo[4 + i] = f2bf(wb[i]); }
  *(u16x8*)(combW + (size_t)h * KC + n8) = lo;
  float s[8] = {};
#pragma unroll
  for (int l = 0; l < L_DIM; ++l) {
    const f32x4* bsrc = (const f32x4*)(beta + ((size_t)h * L_DIM + l) * N_DIM + n8);
    f32x4 a = bsrc[0], b = bsrc[1];
#pragma unroll
    for (int i = 0; i < 4; ++i) { s[i] += a[i] * a[i]; s[4 + i] += b[i] * b[i]; }
  }
  u16x8 hi;
#pragma unroll
  for (int i = 0; i < 8; ++i) hi[i] = f2bf(-0.5f * s[i]);
  *(u16x8*)(combW + (size_t)h * KC + N_DIM + n8) = hi;
}

// ---------- merged GEMM (no atomics) ----------
// bx <  16 : linear — lin[b,h] = [x|x^2]@combW^T + bias, 128x64 tile, K=1024,
//                     plain stores to lin (separate ws buffer). Dispatched first
//                     (longest blocks) for tail balance.
// bx >= 16 : FM     — out[b,h] = 0.5*sum_l s^2, 128x128 tile, K=512,
//                     plain stores to out (each block owns a disjoint 128x16 tile).
// LDS swizzle: row m = 8 chunks of 16B; source chunk c stored at slot c ^ (m&7).
__global__ __launch_bounds__(256) void fused_gemm_kernel(
    const uint16_t* __restrict__ xcomb,   // (B, KC)
    const uint16_t* __restrict__ betab,   // (HL, N)
    const uint16_t* __restrict__ combW,   // (H, KC)
    const float* __restrict__ bias,       // (H,)
    float* __restrict__ out,              // (B, H)
    float* __restrict__ lin)              // (B, H) ws
{
  __shared__ __align__(16) uint16_t As[128 * BK];  // 16 KB
  __shared__ __align__(16) uint16_t Bs[128 * BK];  // 16 KB (linear uses half)

  const int tid  = threadIdx.x;
  const int lane = tid & 63;
  const int wave = tid >> 6;
  const int wm = wave >> 1, wn = wave & 1;
  const int fr   = lane & 15;
  const int quad = lane >> 4;
  const int row0 = blockIdx.y * 128;

  if (blockIdx.x >= 16) {
    // ------- FM part: 128x128, K=512 -------
    const int col0 = (blockIdx.x - 16) * 128;
    f32x4 acc[4][4] = {};
    for (int kt = 0; kt < N_DIM; kt += BK) {
#pragma unroll
      for (int u = 0; u < 4; ++u) {   // A: 1024 chunks
        int s = tid + u * 256, m = s >> 3, cp = s & 7, c = cp ^ (m & 7);
        stage16(xcomb + (size_t)(row0 + m) * KC + kt + c * 8, As + s * 8);
      }
#pragma unroll
      for (int u = 0; u < 4; ++u) {   // B: 1024 chunks
        int s = tid + u * 256, m = s >> 3, cp = s & 7, c = cp ^ (m & 7);
        stage16(betab + (size_t)(col0 + m) * N_DIM + kt + c * 8, Bs + s * 8);
      }
      __syncthreads();
#pragma unroll
      for (int kk = 0; kk < BK; kk += 32) {
        short8 af[4], bf[4];
#pragma unroll
        for (int i = 0; i < 4; ++i) {
          int m = wm * 64 + i * 16 + fr;
          int cp = ((kk >> 3) + quad) ^ (m & 7);
          af[i] = *(const short8*)(As + (m * 8 + cp) * 8);
        }
#pragma unroll
        for (int j = 0; j < 4; ++j) {
          int m = wn * 64 + j * 16 + fr;
          int cp = ((kk >> 3) + quad) ^ (m & 7);
          bf[j] = *(const short8*)(Bs + (m * 8 + cp) * 8);
        }
#pragma unroll
        for (int i = 0; i < 4; ++i)
#pragma unroll
          for (int j = 0; j < 4; ++j)
            acc[i][j] = __builtin_amdgcn_mfma_f32_16x16x32_bf16(af[i], bf[j], acc[i][j], 0, 0, 0);
      }
      __syncthreads();
    }
    // epilogue: C/D layout col=lane&15, row=quad*4+reg. col here is hl = h*8+l.
    const int hcol0 = (blockIdx.x - 16) * 16;
#pragma unroll
    for (int i = 0; i < 4; ++i) {
#pragma unroll
      for (int j = 0; j < 4; ++j) {
        const int h_in = wn * 8 + j * 2 + (fr >> 3);
        const int rowb = row0 + wm * 64 + i * 16 + quad * 4;
#pragma unroll
        for (int r = 0; r < 4; ++r) {
          float v = acc[i][j][r];
          v = v * v;
          v += __shfl_xor(v, 1);   // butterfly over l = lane bits 0..2
          v += __shfl_xor(v, 2);
          v += __shfl_xor(v, 4);
          if ((lane & 7) == 0)
            out[(size_t)(rowb + r) * H_DIM + hcol0 + h_in] = 0.5f * v;
        }
      }
    }
  } else {
    // ------- linear part: 128x64, K=1024 -------
    const int col0 = blockIdx.x * 64;
    f32x4 acc[4][2] = {};
    for (int kt = 0; kt < KC; kt += BK) {
#pragma unroll
      for (int u = 0; u < 4; ++u) {   // A: 1024 chunks
        int s = tid + u * 256, m = s >> 3, cp = s & 7, c = cp ^ (m & 7);
        stage16(xcomb + (size_t)(row0 + m) * KC + kt + c * 8, As + s * 8);
      }
#pragma unroll
      for (int u = 0; u < 2; ++u) {   // B: 512 chunks (64 rows)
        int s = tid + u * 256, m = s >> 3, cp = s & 7, c = cp ^ (m & 7);
        stage16(combW + (size_t)(col0 + m) * KC + kt + c * 8, Bs + s * 8);
      }
      __syncthreads();
#pragma unroll
      for (int kk = 0; kk < BK; kk += 32) {
        short8 af[4], bf[2];
#pragma unroll
        for (int i = 0; i < 4; ++i) {
          int m = wm * 64 + i * 16 + fr;
          int cp = ((kk >> 3) + quad) ^ (m & 7);
          af[i] = *(const short8*)(As + (m * 8 + cp) * 8);
        }
#pragma unroll
        for (int j = 0; j < 2; ++j) {
          int m = wn * 32 + j * 16 + fr;
          int cp = ((kk >> 3) + quad) ^ (m & 7);
          bf[j] = *(const short8*)(Bs + (m * 8 + cp) * 8);
        }
#pragma unroll
        for (int i = 0; i < 4; ++i)
#pragma unroll
          for (int j = 0; j < 2; ++j)
            acc[i][j] = __builtin_amdgcn_mfma_f32_16x16x32_bf16(af[i], bf[j], acc[i][j], 0, 0, 0);
      }
      __syncthreads();
    }
#pragma unroll
    for (int i = 0; i < 4; ++i) {
#pragma unroll
      for (int j = 0; j < 2; ++j) {
        const int col  = col0 + wn * 32 + j * 16 + fr;
        const int rowb = row0 + wm * 64 + i * 16 + quad * 4;
        const float bs = bias[col];
#pragma unroll
        for (int r = 0; r < 4; ++r)
          lin[(size_t)(rowb + r) * H_DIM + col] = acc[i][j][r] + bs;
      }
    }
  }
}

// ---------- final add: out += lin ----------
__global__ void add_kernel(float* __restrict__ out, const float* __restrict__ lin) {
  int idx = blockIdx.x * 256 + threadIdx.x;   // B*H/4 threads
  f32x4 v = ((const f32x4*)lin)[idx];
  f32x4 o = ((f32x4*)out)[idx];
#pragma unroll
  for (int i = 0; i < 4; ++i) o[i] += v[i];
  ((f32x4*)out)[idx] = o;
}

extern "C" void kernel_launch(void* const* d_in, const int* in_sizes, int n_in,
                              void* d_out, int out_size, void* d_ws, size_t ws_size,
                              hipStream_t stream) {
  const float* x    = (const float*)d_in[0];  // (4096, 512)
  const float* beta = (const float*)d_in[1];  // (1024, 8, 512)
  const float* W    = (const float*)d_in[2];  // (1024, 512)
  const float* bias = (const float*)d_in[3];  // (1024,)
  float* out = (float*)d_out;                 // (4096, 1024)

  uint16_t* xcomb = (uint16_t*)d_ws;                        // 4096*1024 bf16 = 8 MB
  uint16_t* betab = xcomb + (size_t)B_DIM * KC;             // 8192*512  bf16 = 8 MB
  uint16_t* combW = betab + (size_t)HL * N_DIM;             // 1024*1024 bf16 = 2 MB
  float*    lin   = (float*)(combW + (size_t)H_DIM * KC);   // 4096*1024 f32  = 16.8 MB

  const int prep_threads = PREP_T0 + PREP_T1 + PREP_T2;     // 851968
  prep_kernel<<<prep_threads / 256, 256, 0, stream>>>(x, beta, W, xcomb, betab, combW);

  // merged GEMM: bx [0,16) = linear 128x64 (K=1024, longest — dispatch first);
  //              bx [16,80) = FM 128x128 (K=512)
  fused_gemm_kernel<<<dim3(80, 32), 256, 0, stream>>>(xcomb, betab, combW, bias, out, lin);

  add_kernel<<<B_DIM * H_DIM / 4 / 256, 256, 0, stream>>>(out, lin);
}

// Round 5
// 164.958 us; speedup vs baseline: 1.4070x; 1.0826x over previous
//
#include <hip/hip_runtime.h>
#include <stdint.h>

// Problem constants (B, N, H, L) = (4096, 512, 1024, 8)
static constexpr int B_DIM = 4096;
static constexpr int N_DIM = 512;
static constexpr int H_DIM = 1024;
static constexpr int L_DIM = 8;
static constexpr int HL    = H_DIM * L_DIM;   // 8192
static constexpr int KC    = 2 * N_DIM;       // 1024: xcomb/combW row length [lo|hi]

typedef __attribute__((ext_vector_type(8))) short short8;     // 8 bf16 (4 VGPRs)
typedef __attribute__((ext_vector_type(8))) unsigned short u16x8;
typedef __attribute__((ext_vector_type(4))) float f32x4;

// round-to-nearest-even fp32 -> bf16 (bit pattern)
__device__ __forceinline__ uint16_t f2bf(float f) {
  uint32_t u = __float_as_uint(f);
  u += 0x7fffu + ((u >> 16) & 1u);
  return (uint16_t)(u >> 16);
}

__device__ __forceinline__ void stage16(const uint16_t* g, uint16_t* l) {
  __builtin_amdgcn_global_load_lds(
      (const __attribute__((address_space(1))) void*)g,
      (__attribute__((address_space(3))) void*)l, 16, 0, 0);
}

// ---------- fused prep kernel (8 elems/thread, 16B stores) ----------
// region 0: betab = bf16(beta)                              (HL*N/8 threads)
// region 1: xcomb[b,0:512]=bf16(x), [512:1024]=bf16(x^2)    (B*N/8)
// region 2: combW[h,0:512]=bf16(W), [512:1024]=bf16(-0.5*sum_l beta^2) (H*N/8)
static constexpr int PREP_T0 = HL * N_DIM / 8;       // 524288
static constexpr int PREP_T1 = B_DIM * N_DIM / 8;    // 262144
static constexpr int PREP_T2 = H_DIM * N_DIM / 8;    // 65536

__global__ void prep_kernel(const float* __restrict__ x, const float* __restrict__ beta,
                            const float* __restrict__ W,
                            uint16_t* __restrict__ xcomb, uint16_t* __restrict__ betab,
                            uint16_t* __restrict__ combW) {
  int t = blockIdx.x * 256 + threadIdx.x;
  if (t < PREP_T0) {                           // beta cast
    const f32x4* src = (const f32x4*)(beta + (size_t)t * 8);
    f32x4 a = src[0], b = src[1];
    u16x8 o;
#pragma unroll
    for (int i = 0; i < 4; ++i) { o[i] = f2bf(a[i]); o[4 + i] = f2bf(b[i]); }
    *(u16x8*)(betab + (size_t)t * 8) = o;
    return;
  }
  t -= PREP_T0;
  if (t < PREP_T1) {                           // x | x^2
    int bb = t >> 6, n8 = (t & 63) * 8;
    const f32x4* src = (const f32x4*)(x + (size_t)bb * N_DIM + n8);
    f32x4 a = src[0], b = src[1];
    u16x8 lo, hi;
#pragma unroll
    for (int i = 0; i < 4; ++i) {
      lo[i] = f2bf(a[i]);        lo[4 + i] = f2bf(b[i]);
      hi[i] = f2bf(a[i] * a[i]); hi[4 + i] = f2bf(b[i] * b[i]);
    }
    *(u16x8*)(xcomb + (size_t)bb * KC + n8)         = lo;
    *(u16x8*)(xcomb + (size_t)bb * KC + N_DIM + n8) = hi;
    return;
  }
  t -= PREP_T1;                                // W | -0.5*sum_l beta^2
  int h = t >> 6, n8 = (t & 63) * 8;
  const f32x4* wsrc = (const f32x4*)(W + (size_t)h * N_DIM + n8);
  f32x4 wa = wsrc[0], wb = wsrc[1];
  u16x8 lo;
#pragma unroll
  for (int i = 0; i < 4; ++i) { lo[i] = f2bf(wa[i]); lo[4 + i] = f2bf(wb[i]); }
  *(u16x8*)(combW + (size_t)h * KC + n8) = lo;
  float s[8] = {};
#pragma unroll
  for (int l = 0; l < L_DIM; ++l) {
    const f32x4* bsrc = (const f32x4*)(beta + ((size_t)h * L_DIM + l) * N_DIM + n8);
    f32x4 a = bsrc[0], b = bsrc[1];
#pragma unroll
    for (int i = 0; i < 4; ++i) { s[i] += a[i] * a[i]; s[4 + i] += b[i] * b[i]; }
  }
  u16x8 hi;
#pragma unroll
  for (int i = 0; i < 8; ++i) hi[i] = f2bf(-0.5f * s[i]);
  *(u16x8*)(combW + (size_t)h * KC + N_DIM + n8) = hi;
}

// ---------- single fused GEMM: FM + linear, one uniform grid ----------
// Block (bx, by): 128 b-rows (row0=by*128) x 128 hl-cols (col0=bx*128 of betab)
//                 = 16 h outputs (hcol0=bx*16), PLUS the same block's 128x16
//                 linear tile, K-reordered into the same kt loop:
//   lin(b,h) = sum_{k<512} x_k*Wlo_k  (wn=0 waves, reuse FM A-frags)
//            + sum_{k<512} x2_k*Whi_k (wn=1 waves, A-frags from x^2 half)
// LDS tiles (all XOR-swizzled so quad reads are 2-way = free):
//   As 128x128 (x | x^2 halves), slot = c ^ (m&15)
//   Bs 128x64  (betab),          slot = c ^ (m&7)
//   Ws 16x128  (combW lo|hi),    slot = c ^ m
// Epilogue: lin partials (wn0 store, wn1 add) + FM butterfly add meet in an
// 8 KB LDS tile (reusing As), then coalesced f32 stores with bias.
__global__ __launch_bounds__(256) void fm_kernel(
    const uint16_t* __restrict__ xcomb,   // (B, KC)
    const uint16_t* __restrict__ betab,   // (HL, N)
    const uint16_t* __restrict__ combW,   // (H, KC)
    const float* __restrict__ bias,       // (H,)
    float* __restrict__ out)              // (B, H)
{
  __shared__ __align__(16) uint16_t As[128 * 128];  // 32 KB
  __shared__ __align__(16) uint16_t Bs[128 * 64];   // 16 KB
  __shared__ __align__(16) uint16_t Ws[16 * 128];   //  4 KB

  const int tid  = threadIdx.x;
  const int lane = tid & 63;
  const int wave = tid >> 6;
  const int wm = wave >> 1, wn = wave & 1;
  const int fr   = lane & 15;
  const int quad = lane >> 4;
  const int row0  = blockIdx.y * 128;
  const int col0  = blockIdx.x * 128;   // betab row base (hl)
  const int hcol0 = blockIdx.x * 16;    // h base

  f32x4 acc[4][4] = {};
  f32x4 lacc[4]   = {};

  for (int kt = 0; kt < N_DIM; kt += 64) {
    // A: both halves (x at cols kt.., x^2 at cols 512+kt..), 2048 chunks
#pragma unroll
    for (int u = 0; u < 8; ++u) {
      int s = tid + u * 256, m = s >> 4, cp = s & 15, c = cp ^ (m & 15);
      int col = (c >> 3) * N_DIM + kt + (c & 7) * 8;
      stage16(xcomb + (size_t)(row0 + m) * KC + col, As + s * 8);
    }
    // B: betab tile, 1024 chunks
#pragma unroll
    for (int u = 0; u < 4; ++u) {
      int s = tid + u * 256, m = s >> 3, cp = s & 7, c = cp ^ (m & 7);
      stage16(betab + (size_t)(col0 + m) * N_DIM + kt + c * 8, Bs + s * 8);
    }
    // W: combW 16 rows, both halves, 256 chunks
    {
      int m = tid >> 4, cp = tid & 15, c = cp ^ m;
      int col = (c >> 3) * N_DIM + kt + (c & 7) * 8;
      stage16(combW + (size_t)(hcol0 + m) * KC + col, Ws + tid * 8);
    }
    __syncthreads();

#pragma unroll
    for (int kk2 = 0; kk2 < 2; ++kk2) {
      const int cbase = kk2 * 4 + quad;
      short8 af[4], bf[4], al[4], wf;
#pragma unroll
      for (int i = 0; i < 4; ++i) {
        int m = wm * 64 + i * 16 + fr;
        af[i] = *(const short8*)(As + (m * 16 + (cbase ^ (m & 15))) * 8);
      }
#pragma unroll
      for (int j = 0; j < 4; ++j) {
        int m = wn * 64 + j * 16 + fr;
        bf[j] = *(const short8*)(Bs + (m * 8 + (cbase ^ (m & 7))) * 8);
      }
      wf = *(const short8*)(Ws + (fr * 16 + ((wn * 8 + cbase) ^ fr)) * 8);
      if (wn == 0) {        // x-half: reuse FM A-frags (same chunks)
#pragma unroll
        for (int i = 0; i < 4; ++i) al[i] = af[i];
      } else {              // x^2-half chunks 8..15
#pragma unroll
        for (int i = 0; i < 4; ++i) {
          int m = wm * 64 + i * 16 + fr;
          al[i] = *(const short8*)(As + (m * 16 + ((8 + cbase) ^ (m & 15))) * 8);
        }
      }
#pragma unroll
      for (int i = 0; i < 4; ++i)
#pragma unroll
        for (int j = 0; j < 4; ++j)
          acc[i][j] = __builtin_amdgcn_mfma_f32_16x16x32_bf16(af[i], bf[j], acc[i][j], 0, 0, 0);
#pragma unroll
      for (int i = 0; i < 4; ++i)
        lacc[i] = __builtin_amdgcn_mfma_f32_16x16x32_bf16(al[i], wf, lacc[i], 0, 0, 0);
    }
    __syncthreads();
  }

  // ---- epilogue: combine lin partials + FM in LDS, coalesced store ----
  float* red = (float*)As;   // 128 x 16 f32 = 8 KB (As free after last sync)
  if (wn == 0) {
#pragma unroll
    for (int i = 0; i < 4; ++i)
#pragma unroll
      for (int r = 0; r < 4; ++r)
        red[(wm * 64 + i * 16 + quad * 4 + r) * 16 + fr] = lacc[i][r];
  }
  __syncthreads();
  if (wn == 1) {
#pragma unroll
    for (int i = 0; i < 4; ++i)
#pragma unroll
      for (int r = 0; r < 4; ++r)
        red[(wm * 64 + i * 16 + quad * 4 + r) * 16 + fr] += lacc[i][r];
  }
  __syncthreads();
  // FM: C/D layout col=lane&15 (hl-local), row=quad*4+reg; butterfly over l bits
#pragma unroll
  for (int i = 0; i < 4; ++i)
#pragma unroll
    for (int j = 0; j < 4; ++j) {
      const int hin = wn * 8 + j * 2 + (fr >> 3);
#pragma unroll
      for (int r = 0; r < 4; ++r) {
        float v = acc[i][j][r];
        v = v * v;
        v += __shfl_xor(v, 1);
        v += __shfl_xor(v, 2);
        v += __shfl_xor(v, 4);
        if ((lane & 7) == 0)
          red[(wm * 64 + i * 16 + quad * 4 + r) * 16 + hin] += 0.5f * v;
      }
    }
  __syncthreads();
#pragma unroll
  for (int e = tid; e < 2048; e += 256) {
    int r = e >> 4, hc = e & 15;
    out[(size_t)(row0 + r) * H_DIM + hcol0 + hc] = red[e] + bias[hcol0 + hc];
  }
}

extern "C" void kernel_launch(void* const* d_in, const int* in_sizes, int n_in,
                              void* d_out, int out_size, void* d_ws, size_t ws_size,
                              hipStream_t stream) {
  const float* x    = (const float*)d_in[0];  // (4096, 512)
  const float* beta = (const float*)d_in[1];  // (1024, 8, 512)
  const float* W    = (const float*)d_in[2];  // (1024, 512)
  const float* bias = (const float*)d_in[3];  // (1024,)
  float* out = (float*)d_out;                 // (4096, 1024)

  uint16_t* xcomb = (uint16_t*)d_ws;                        // 4096*1024 bf16 = 8 MB
  uint16_t* betab = xcomb + (size_t)B_DIM * KC;             // 8192*512  bf16 = 8 MB
  uint16_t* combW = betab + (size_t)HL * N_DIM;             // 1024*1024 bf16 = 2 MB

  const int prep_threads = PREP_T0 + PREP_T1 + PREP_T2;     // 851968
  prep_kernel<<<prep_threads / 256, 256, 0, stream>>>(x, beta, W, xcomb, betab, combW);

  // one uniform GEMM: 2048 identical blocks (8 rounds/CU), FM + linear fused
  fm_kernel<<<dim3(HL / 128, B_DIM / 128), 256, 0, stream>>>(
      xcomb, betab, combW, bias, out);
}